// Round 1
// baseline (126.968 us; speedup 1.0000x reference)
//
#include <hip/hip_runtime.h>

// res[i,f,h] = sum_{m,n} cgc[m,n,h] * x[i,f,m] * y[i,f,n]
// N_ATOMS=100000, N_CHAN=128, DIM_L1=3, DIM_L2=3, DIM_L3=5. All fp32.
// Memory-bound: 563 MB traffic vs ~1.3 GFLOP. One thread = 4 (i,f) pairs
// so all global accesses are aligned float4.

constexpr int N_PAIRS = 100000 * 128;   // 12,800,000 (i,f) pairs
constexpr int GROUPS  = N_PAIRS / 4;    // 3,200,000 — exact, no tail

__global__ __launch_bounds__(256) void tp_contract_kernel(
    const float* __restrict__ x,
    const float* __restrict__ y,
    const float* __restrict__ cgc,
    float* __restrict__ out)
{
    // cgc is tiny (45 floats) and wave-uniform: fully unrolled loads,
    // compiler scalarizes to SGPR s_load.
    float c[3][3][5];
#pragma unroll
    for (int m = 0; m < 3; ++m)
#pragma unroll
        for (int n = 0; n < 3; ++n)
#pragma unroll
            for (int h = 0; h < 5; ++h)
                c[m][n][h] = cgc[(m * 3 + n) * 5 + h];

    const int stride = gridDim.x * blockDim.x;
    for (int g = blockIdx.x * blockDim.x + threadIdx.x; g < GROUPS; g += stride) {
        // 4 pairs: 12 floats of x, 12 of y (3 aligned float4 each)
        const float4* xp = reinterpret_cast<const float4*>(x + (size_t)g * 12);
        const float4* yp = reinterpret_cast<const float4*>(y + (size_t)g * 12);
        float4 xv0 = xp[0], xv1 = xp[1], xv2 = xp[2];
        float4 yv0 = yp[0], yv1 = yp[1], yv2 = yp[2];

        float xs[12] = { xv0.x, xv0.y, xv0.z, xv0.w,
                         xv1.x, xv1.y, xv1.z, xv1.w,
                         xv2.x, xv2.y, xv2.z, xv2.w };
        float ys[12] = { yv0.x, yv0.y, yv0.z, yv0.w,
                         yv1.x, yv1.y, yv1.z, yv1.w,
                         yv2.x, yv2.y, yv2.z, yv2.w };

        float o[20];
#pragma unroll
        for (int p = 0; p < 4; ++p) {
            float acc[5] = {0.f, 0.f, 0.f, 0.f, 0.f};
#pragma unroll
            for (int m = 0; m < 3; ++m) {
#pragma unroll
                for (int n = 0; n < 3; ++n) {
                    const float xy = xs[p * 3 + m] * ys[p * 3 + n];
#pragma unroll
                    for (int h = 0; h < 5; ++h)
                        acc[h] = fmaf(c[m][n][h], xy, acc[h]);
                }
            }
#pragma unroll
            for (int h = 0; h < 5; ++h) o[p * 5 + h] = acc[h];
        }

        // 4 pairs * 5 outputs = 20 floats = 5 aligned float4 stores
        float4* op = reinterpret_cast<float4*>(out + (size_t)g * 20);
#pragma unroll
        for (int q = 0; q < 5; ++q) {
            op[q] = make_float4(o[q * 4 + 0], o[q * 4 + 1],
                                o[q * 4 + 2], o[q * 4 + 3]);
        }
    }
}

extern "C" void kernel_launch(void* const* d_in, const int* in_sizes, int n_in,
                              void* d_out, int out_size, void* d_ws, size_t ws_size,
                              hipStream_t stream) {
    const float* x   = (const float*)d_in[0];
    const float* y   = (const float*)d_in[1];
    const float* cgc = (const float*)d_in[2];
    float* out = (float*)d_out;

    const int block = 256;
    int grid = (GROUPS + block - 1) / block;
    if (grid > 2048) grid = 2048;   // grid-stride the rest
    tp_contract_kernel<<<grid, block, 0, stream>>>(x, y, cgc, out);
}

// Round 2
// 105.927 us; speedup vs baseline: 1.1986x; 1.1986x over previous
//
#include <hip/hip_runtime.h>

// res[i,f,h] = sum_{m,n} cgc[m,n,h] * x[i,f,m] * y[i,f,n]
// N_ATOMS=100000, N_CHAN=128, DIM_L1=3, DIM_L2=3, DIM_L3=5. All fp32.
//
// Memory-bound (563 MB logical vs 1.3 GFLOP). Round-1 kernel hit only
// 2.8 TB/s: lane-stride-48B loads / stride-80B stores inflate L1/TA
// transactions 3-5x. This version stages tiles through LDS so every
// GLOBAL access is lane-contiguous float4 (16 B/lane):
//   block = 1024 pairs; load 2x768 float4 coalesced -> LDS,
//   per-thread compute from LDS, stage 1280 float4 out -> LDS (union),
//   coalesced store. 24 KB LDS -> 6 blocks/CU.

constexpr int N_PAIRS = 100000 * 128;          // 12,800,000
constexpr int PAIRS_PER_BLOCK = 1024;          // 256 threads * 4 pairs
constexpr int NBLOCKS = N_PAIRS / PAIRS_PER_BLOCK; // 12,500 exact, no tail

__global__ __launch_bounds__(256) void tp_contract_kernel(
    const float* __restrict__ x,
    const float* __restrict__ y,
    const float* __restrict__ cgc,
    float* __restrict__ out)
{
    // union buffer: phase A = x tile (float4[768]) + y tile (float4[768]) = 24 KB
    //               phase B = out tile (float4[1280]) = 20 KB
    __shared__ float4 smem[1536];

    const int tid = threadIdx.x;
    const size_t blk = blockIdx.x;

    // cgc: 45 floats, wave-uniform address -> scalarized to SGPRs (R1: SGPR=112)
    float c[3][3][5];
#pragma unroll
    for (int m = 0; m < 3; ++m)
#pragma unroll
        for (int n = 0; n < 3; ++n)
#pragma unroll
            for (int h = 0; h < 5; ++h)
                c[m][n][h] = cgc[(m * 3 + n) * 5 + h];

    // ---- phase 1: coalesced global -> LDS (lane stride 16 B) ----
    const float4* gx = reinterpret_cast<const float4*>(x) + blk * 768;
    const float4* gy = reinterpret_cast<const float4*>(y) + blk * 768;
#pragma unroll
    for (int j = 0; j < 3; ++j) {
        smem[j * 256 + tid]       = gx[j * 256 + tid];
        smem[768 + j * 256 + tid] = gy[j * 256 + tid];
    }
    __syncthreads();

    // ---- phase 2: per-thread fragment from LDS (3+3 ds_read_b128) ----
    float4 xv0 = smem[tid * 3 + 0];
    float4 xv1 = smem[tid * 3 + 1];
    float4 xv2 = smem[tid * 3 + 2];
    float4 yv0 = smem[768 + tid * 3 + 0];
    float4 yv1 = smem[768 + tid * 3 + 1];
    float4 yv2 = smem[768 + tid * 3 + 2];

    float xs[12] = { xv0.x, xv0.y, xv0.z, xv0.w,
                     xv1.x, xv1.y, xv1.z, xv1.w,
                     xv2.x, xv2.y, xv2.z, xv2.w };
    float ys[12] = { yv0.x, yv0.y, yv0.z, yv0.w,
                     yv1.x, yv1.y, yv1.z, yv1.w,
                     yv2.x, yv2.y, yv2.z, yv2.w };

    float o[20];
#pragma unroll
    for (int p = 0; p < 4; ++p) {
        float acc[5] = {0.f, 0.f, 0.f, 0.f, 0.f};
#pragma unroll
        for (int m = 0; m < 3; ++m) {
#pragma unroll
            for (int n = 0; n < 3; ++n) {
                const float xy = xs[p * 3 + m] * ys[p * 3 + n];
#pragma unroll
                for (int h = 0; h < 5; ++h)
                    acc[h] = fmaf(c[m][n][h], xy, acc[h]);
            }
        }
#pragma unroll
        for (int h = 0; h < 5; ++h) o[p * 5 + h] = acc[h];
    }

    __syncthreads();   // everyone done reading x/y tiles before overwrite

    // ---- phase 3: stage outputs to LDS (5 ds_write_b128) ----
#pragma unroll
    for (int q = 0; q < 5; ++q)
        smem[tid * 5 + q] = make_float4(o[q * 4 + 0], o[q * 4 + 1],
                                        o[q * 4 + 2], o[q * 4 + 3]);
    __syncthreads();

    // ---- phase 4: coalesced LDS -> global (lane stride 16 B) ----
    float4* go = reinterpret_cast<float4*>(out) + blk * 1280;
#pragma unroll
    for (int j = 0; j < 5; ++j)
        go[j * 256 + tid] = smem[j * 256 + tid];
}

extern "C" void kernel_launch(void* const* d_in, const int* in_sizes, int n_in,
                              void* d_out, int out_size, void* d_ws, size_t ws_size,
                              hipStream_t stream) {
    const float* x   = (const float*)d_in[0];
    const float* y   = (const float*)d_in[1];
    const float* cgc = (const float*)d_in[2];
    float* out = (float*)d_out;

    tp_contract_kernel<<<NBLOCKS, 256, 0, stream>>>(x, y, cgc, out);
}

// Round 3
// 93.269 us; speedup vs baseline: 1.3613x; 1.1357x over previous
//
#include <hip/hip_runtime.h>
#include <string.h>

// res[i,f,h] = sum_{m,n} cgc[m,n,h] * x[i,f,m] * y[i,f,n]
// N_ATOMS=100000, N_CHAN=128, DIM_L1=3, DIM_L2=3, DIM_L3=5. All fp32.
//
// Memory-bound. R2 (LDS-staged, 3 barriers): 106 us. This version:
//  - phase 1 staging via global_load_lds (direct-to-LDS DMA, no VGPR trip)
//  - ONE barrier per block: after it, all LDS traffic is wave-private
//    (thread t's fragment = smem[3t..3t+2]; wave w's output range
//    [320w,320w+320) is produced by wave w's own threads), so output
//    staging reuses the wave's own consumed x/y chunks with same-wave
//    in-order DS semantics -- no further barriers.
//  - non-temporal output stores: output is write-only 256 MB; keep it
//    from evicting the 307 MB of inputs that re-read from L3 each replay.

constexpr int N_PAIRS = 100000 * 128;              // 12,800,000
constexpr int PAIRS_PER_BLOCK = 1024;              // 256 threads * 4 pairs
constexpr int NBLOCKS = N_PAIRS / PAIRS_PER_BLOCK; // 12,500 exact, no tail

typedef float vf4 __attribute__((ext_vector_type(4)));

__global__ __launch_bounds__(256) void tp_contract_kernel(
    const float* __restrict__ x,
    const float* __restrict__ y,
    const float* __restrict__ cgc,
    float* __restrict__ out)
{
    __shared__ float4 smem[1536];   // 24 KB union

    const int tid  = threadIdx.x;
    const int lane = tid & 63;
    const int w    = tid >> 6;
    const size_t blk = blockIdx.x;

    float c[3][3][5];
#pragma unroll
    for (int m = 0; m < 3; ++m)
#pragma unroll
        for (int n = 0; n < 3; ++n)
#pragma unroll
            for (int h = 0; h < 5; ++h)
                c[m][n][h] = cgc[(m * 3 + n) * 5 + h];

    // ---- phase 1: global -> LDS direct DMA (lane stride 16 B, linear dest) ----
    const float4* gx = reinterpret_cast<const float4*>(x) + blk * 768;
    const float4* gy = reinterpret_cast<const float4*>(y) + blk * 768;
#pragma unroll
    for (int j = 0; j < 3; ++j) {
        __builtin_amdgcn_global_load_lds(
            (const __attribute__((address_space(1))) void*)(gx + j * 256 + w * 64 + lane),
            (__attribute__((address_space(3))) void*)(&smem[j * 256 + w * 64]),
            16, 0, 0);
        __builtin_amdgcn_global_load_lds(
            (const __attribute__((address_space(1))) void*)(gy + j * 256 + w * 64 + lane),
            (__attribute__((address_space(3))) void*)(&smem[768 + j * 256 + w * 64]),
            16, 0, 0);
    }
    __syncthreads();   // the ONLY barrier

    // ---- phase 2: per-thread fragment (conflict-free b128 reads) ----
    float4 xv0 = smem[tid * 3 + 0];
    float4 xv1 = smem[tid * 3 + 1];
    float4 xv2 = smem[tid * 3 + 2];
    float4 yv0 = smem[768 + tid * 3 + 0];
    float4 yv1 = smem[768 + tid * 3 + 1];
    float4 yv2 = smem[768 + tid * 3 + 2];

    float xs[12] = { xv0.x, xv0.y, xv0.z, xv0.w,
                     xv1.x, xv1.y, xv1.z, xv1.w,
                     xv2.x, xv2.y, xv2.z, xv2.w };
    float ys[12] = { yv0.x, yv0.y, yv0.z, yv0.w,
                     yv1.x, yv1.y, yv1.z, yv1.w,
                     yv2.x, yv2.y, yv2.z, yv2.w };

    float o[20];
#pragma unroll
    for (int p = 0; p < 4; ++p) {
        float acc[5] = {0.f, 0.f, 0.f, 0.f, 0.f};
#pragma unroll
        for (int m = 0; m < 3; ++m) {
#pragma unroll
            for (int n = 0; n < 3; ++n) {
                const float xy = xs[p * 3 + m] * ys[p * 3 + n];
#pragma unroll
                for (int h = 0; h < 5; ++h)
                    acc[h] = fmaf(c[m][n][h], xy, acc[h]);
            }
        }
#pragma unroll
        for (int h = 0; h < 5; ++h) o[p * 5 + h] = acc[h];
    }

    // ---- phase 3: wave-private out staging (no barrier) ----
    //   local out-float4 index o = 5*lane + q, o in [0,320)
    //   o < 192 -> smem[w*192 + o]        (wave's own x chunk)
    //   o >=192 -> smem[768 + w*192 + o-192] (wave's own y chunk)
#pragma unroll
    for (int q = 0; q < 5; ++q) {
        const int oidx = lane * 5 + q;
        const int a = (oidx < 192) ? (w * 192 + oidx)
                                   : (768 + w * 192 + (oidx - 192));
        smem[a] = make_float4(o[q * 4 + 0], o[q * 4 + 1],
                              o[q * 4 + 2], o[q * 4 + 3]);
    }

    // ---- phase 4: wave-coalesced non-temporal stores ----
    float4* go = reinterpret_cast<float4*>(out) + blk * 1280 + (size_t)w * 320;
#pragma unroll
    for (int j = 0; j < 5; ++j) {
        const int oidx = j * 64 + lane;
        const int a = (oidx < 192) ? (w * 192 + oidx)
                                   : (768 + w * 192 + (oidx - 192));
        float4 v = smem[a];
        vf4 vv;
        memcpy(&vv, &v, 16);
        __builtin_nontemporal_store(vv, reinterpret_cast<vf4*>(&go[j * 64 + lane]));
    }
}

extern "C" void kernel_launch(void* const* d_in, const int* in_sizes, int n_in,
                              void* d_out, int out_size, void* d_ws, size_t ws_size,
                              hipStream_t stream) {
    const float* x   = (const float*)d_in[0];
    const float* y   = (const float*)d_in[1];
    const float* cgc = (const float*)d_in[2];
    float* out = (float*)d_out;

    tp_contract_kernel<<<NBLOCKS, 256, 0, stream>>>(x, y, cgc, out);
}